// Round 4
// baseline (1210.801 us; speedup 1.0000x reference)
//
#include <hip/hip_runtime.h>
#include <hip/hip_bf16.h>
#include <stdint.h>

// LMHA: linear multi-head attention (elu+1), S=2048 B=16 D=1024 H=8 dh=128
// R4 (bisection 2): R3 byte-identical EXCEPT kv_kernel replaced by kv_simple —
// a trivially-correct VALU kv (no MFMA, no LDS transpose, no z-fusion).
// Purpose: decide whether the shared R2/R3 bug (absmax 1.7734 both rounds)
// is in the nt-kv kernel or in the Ctile-relayout epilogues.

typedef __bf16 bf16x8 __attribute__((ext_vector_type(8)));
typedef float f32x4 __attribute__((ext_vector_type(4)));

#define S_LEN 2048
#define B_SZ  16
#define D_MOD 1024
#define N_H   8
#define D_H   128

__device__ __forceinline__ short f2bf(float f) {
  __bf16 b = (__bf16)f;
  return __builtin_bit_cast(short, b);
}
__device__ __forceinline__ float bf2f(short s) {
  return (float)__builtin_bit_cast(__bf16, s);
}

// ---------------- prep: h = bf16(x + pos_encoding) ----------------
__global__ void prep_h(const float* __restrict__ x, short* __restrict__ h) {
  size_t idx8 = (size_t)blockIdx.x * blockDim.x + threadIdx.x;
  size_t base = idx8 * 8;
  int d = (int)(base & 1023);
  int r = (int)(base >> 10);
  int s = r >> 4;
  float4 v0 = *(const float4*)(x + base);
  float4 v1 = *(const float4*)(x + base + 4);
  float vs[8] = {v0.x, v0.y, v0.z, v0.w, v1.x, v1.y, v1.z, v1.w};
  const float kdiv = -9.210340371976184f / 1024.0f;
  bf16x8 ov;
#pragma unroll
  for (int t = 0; t < 8; ++t) {
    int dc = d + t;
    float div = __expf((float)(dc & ~1) * kdiv);
    float ang = (float)s * div;
    float pe = (dc & 1) ? __cosf(ang) : __sinf(ang);
    ov[t] = (__bf16)(vs[t] + pe);
  }
  *(bf16x8*)(h + base) = ov;
}

// ---------------- pack weights to bf16: [Wq;Wk;Wv;Wo] = [4096,1024] ----------------
__global__ void pack_w(const float* __restrict__ Wq, const float* __restrict__ Wk,
                       const float* __restrict__ Wv, const float* __restrict__ Wo,
                       short* __restrict__ Wcat) {
  size_t i4 = (size_t)blockIdx.x * blockDim.x + threadIdx.x;
  size_t base = i4 * 4;
  const float* src;
  size_t off;
  if (base < 1048576)      { src = Wq; off = base; }
  else if (base < 2097152) { src = Wk; off = base - 1048576; }
  else if (base < 3145728) { src = Wv; off = base - 2097152; }
  else                     { src = Wo; off = base - 3145728; }
  float4 v = *(const float4*)(src + off);
  alignas(8) short o[4] = {f2bf(v.x), f2bf(v.y), f2bf(v.z), f2bf(v.w)};
  *(uint2*)(Wcat + base) = *(const uint2*)o;
}

// ---------------- PROVEN R1 GEMM core: 128x128 tile, bt-form, stride-40 LDS ----------------
template <int K>
__device__ __forceinline__ void gemm_core_128(const short* __restrict__ A,
                                              const short* __restrict__ W,
                                              short* As, short* Ws,
                                              f32x4 (&acc)[4][4]) {
  const int tid = threadIdx.x;
  const int c8 = tid & 3, r0 = tid >> 2;
  const int lane = tid & 63;
  const int wm = (tid >> 6) & 1, wn = tid >> 7;
  const int l15 = lane & 15, quad = lane >> 4;
  const size_t aoff = (size_t)r0 * K + c8 * 8;
  const size_t astep = (size_t)64 * K;

  for (int k0 = 0; k0 < K; k0 += 32) {
    uint4 a0 = *(const uint4*)(A + aoff + k0);
    uint4 a1 = *(const uint4*)(A + aoff + astep + k0);
    uint4 w0 = *(const uint4*)(W + aoff + k0);
    uint4 w1 = *(const uint4*)(W + aoff + astep + k0);
    __syncthreads();
    *(uint4*)&As[r0 * 40 + c8 * 8] = a0;
    *(uint4*)&As[(r0 + 64) * 40 + c8 * 8] = a1;
    *(uint4*)&Ws[r0 * 40 + c8 * 8] = w0;
    *(uint4*)&Ws[(r0 + 64) * 40 + c8 * 8] = w1;
    __syncthreads();
    bf16x8 af[4], wf[4];
#pragma unroll
    for (int i = 0; i < 4; ++i)
      af[i] = *(const bf16x8*)&As[(wm * 64 + i * 16 + l15) * 40 + quad * 8];
#pragma unroll
    for (int j = 0; j < 4; ++j)
      wf[j] = *(const bf16x8*)&Ws[(wn * 64 + j * 16 + l15) * 40 + quad * 8];
#pragma unroll
    for (int i = 0; i < 4; ++i)
#pragma unroll
      for (int j = 0; j < 4; ++j)
        acc[i][j] = __builtin_amdgcn_mfma_f32_16x16x32_bf16(af[i], wf[j], acc[i][j], 0, 0, 0);
  }
}

// ---------------- GEMM1: qkv = h @ Wqkv^T, fused bias+elu, outputs [B,H,S,dh] ----------------
__launch_bounds__(256)
__global__ void gemm_qkv(const short* __restrict__ h, const short* __restrict__ Wqkv,
                         const float* __restrict__ bq, const float* __restrict__ bk,
                         const float* __restrict__ bv,
                         short* __restrict__ pq, short* __restrict__ pk,
                         short* __restrict__ v) {
  __shared__ alignas(16) short smem[16384]; // As 5120 | Ws 5120 ; reused as Ctile 16384
  short* As = smem;
  short* Ws = smem + 5120;
  const int bn = blockIdx.x; // 0..23
  const int bm = blockIdx.y; // 0..255
  const int rowBase = bm * 128, colBase = bn * 128;

  f32x4 acc[4][4] = {};
  gemm_core_128<1024>(h + (size_t)rowBase * 1024, Wqkv + (size_t)colBase * 1024, As, Ws, acc);

  const int tid = threadIdx.x;
  const int lane = tid & 63;
  const int wm = (tid >> 6) & 1, wn = tid >> 7;
  const int l15 = lane & 15, quad = lane >> 4;

  const int p = colBase >> 10;        // 0:q 1:k 2:v
  const int hh = (colBase >> 7) & 7;  // head
  const float* bias = (p == 0) ? bq : (p == 1) ? bk : bv;
  short* dst = (p == 0) ? pq : (p == 1) ? pk : v;
  const bool act = (p < 2);

  __syncthreads(); // WAR: all waves' LDS frag reads done before Ctile overwrites As/Ws
  short* Ctile = smem; // 128x128 bf16, stride 128
#pragma unroll
  for (int j = 0; j < 4; ++j) {
    const int e = wn * 64 + j * 16 + l15;
    const float bval = bias[hh * 128 + e];
#pragma unroll
    for (int i = 0; i < 4; ++i) {
#pragma unroll
      for (int r = 0; r < 4; ++r) {
        int row = wm * 64 + i * 16 + quad * 4 + r;
        float val = acc[i][j][r] + bval;
        if (act) val = val > 0.f ? val + 1.f : __expf(val);
        Ctile[row * 128 + e] = f2bf(val);
      }
    }
  }
  __syncthreads();
  // coalesced store: 16 lanes x 16B = full 256B row per group
#pragma unroll
  for (int g = 0; g < 8; ++g) {
    int rr = g * 16 + (tid >> 4);
    int e0 = (tid & 15) * 8;
    uint4 val = *(const uint4*)(Ctile + rr * 128 + e0);
    int grow = rowBase + rr;
    int s = grow >> 4, b = grow & 15;
    *(uint4*)(dst + (((size_t)b * N_H + hh) * S_LEN + s) * D_H + e0) = val;
  }
}

// ---------------- kv_simple: trivially-correct VALU kv + z (bisection probe) ----------------
// kvW[bh][e][d] = sum_s pk[s][d] * v[s][e]; z[bh][d] = sum_s pk[s][d].
// Block = (bh, e-half). Thread t: d = t&127, e-range = 32*(half*2 + t>>7) .. +31.
__launch_bounds__(256)
__global__ void kv_simple(const short* __restrict__ pk, const short* __restrict__ v,
                          short* __restrict__ kvW, float* __restrict__ z) {
  const int bx = blockIdx.x;        // 0..255
  const int bh = bx >> 1, half = bx & 1;
  const int t = threadIdx.x;
  const int d = t & 127;
  const int esub = t >> 7;          // 0/1
  const int e0 = half * 64 + esub * 32;
  const short* pkb = pk + (size_t)bh * S_LEN * D_H;
  const short* vb  = v  + (size_t)bh * S_LEN * D_H;
  float acc[32] = {};
  float zsum = 0.f;
  for (int s = 0; s < S_LEN; ++s) {
    float pkv = bf2f(pkb[(size_t)s * D_H + d]);   // coalesced across lanes
    zsum += pkv;
    const bf16x8* vrow = (const bf16x8*)(vb + (size_t)s * D_H + e0); // wave-broadcast
#pragma unroll
    for (int c = 0; c < 4; ++c) {
      bf16x8 vv = vrow[c];
#pragma unroll
      for (int j = 0; j < 8; ++j) acc[c * 8 + j] += pkv * (float)vv[j];
    }
  }
  short* kvb = kvW + (size_t)bh * (D_H * D_H);
#pragma unroll
  for (int j = 0; j < 32; ++j)
    kvb[(size_t)(e0 + j) * D_H + d] = f2bf(acc[j]);  // lanes over d: coalesced rows
  if (half == 0 && esub == 0) z[bh * D_H + d] = zsum;
}

// ---------------- attn: att = (pq @ kvW^T) / (pq . z + eps), out layout [S*B, D] ----------------
__launch_bounds__(256)
__global__ void attn_kernel(const short* __restrict__ pq, const short* __restrict__ kvW,
                            const float* __restrict__ z, short* __restrict__ att) {
  __shared__ alignas(16) short smem[16384];
  __shared__ float den_lds[128];
  __shared__ float z_lds[128];
  short* As = smem;
  short* Ws = smem + 5120;
  const int s0 = blockIdx.x * 128;
  const int bh = blockIdx.y;
  const int tid = threadIdx.x;
  if (tid < 128) z_lds[tid] = z[bh * D_H + tid];

  const short* Abase = pq + ((size_t)bh * S_LEN + s0) * D_H;
  const short* Wbase = kvW + (size_t)bh * (D_H * D_H);

  f32x4 acc[4][4] = {};
  gemm_core_128<128>(Abase, Wbase, As, Ws, acc);

  // den[s] = pq[s] . z + eps  (global re-read, L2-hot)
  if (tid < 128) {
    const short* prow = Abase + (size_t)tid * D_H;
    float sum = 0.f;
#pragma unroll
    for (int d = 0; d < D_H; d += 8) {
      bf16x8 vv = *(const bf16x8*)(prow + d);
#pragma unroll
      for (int t = 0; t < 8; ++t) sum += (float)vv[t] * z_lds[d + t];
    }
    den_lds[tid] = sum + 1e-6f;
  }
  __syncthreads(); // den visible + WAR: all frag reads done before Ctile overwrite

  const int lane = tid & 63;
  const int wm = (tid >> 6) & 1, wn = tid >> 7;
  const int l15 = lane & 15, quad = lane >> 4;
  short* Ctile = smem;
#pragma unroll
  for (int j = 0; j < 4; ++j) {
    const int e = wn * 64 + j * 16 + l15;
#pragma unroll
    for (int i = 0; i < 4; ++i) {
#pragma unroll
      for (int r = 0; r < 4; ++r) {
        int row = wm * 64 + i * 16 + quad * 4 + r;
        Ctile[row * 128 + e] = f2bf(acc[i][j][r] / den_lds[row]);
      }
    }
  }
  __syncthreads();
  const int b = bh >> 3, hd = bh & 7;
#pragma unroll
  for (int g = 0; g < 8; ++g) {
    int rr = g * 16 + (tid >> 4);
    int e0 = (tid & 15) * 8;
    uint4 val = *(const uint4*)(Ctile + rr * 128 + e0);
    *(uint4*)(att + ((size_t)(s0 + rr) * B_SZ + b) * D_MOD + hd * D_H + e0) = val;
  }
}

// ---------------- out = att @ Wo^T + bo (fp32, direct stores) ----------------
__launch_bounds__(256)
__global__ void gemm_out(const short* __restrict__ att, const short* __restrict__ WoB,
                         const float* __restrict__ bo, float* __restrict__ out) {
  __shared__ alignas(16) short smem[10240];
  short* As = smem;
  short* Ws = smem + 5120;
  const int bn = blockIdx.x; // 0..7
  const int bm = blockIdx.y; // 0..255
  const int rowBase = bm * 128, colBase = bn * 128;

  f32x4 acc[4][4] = {};
  gemm_core_128<1024>(att + (size_t)rowBase * 1024, WoB + (size_t)colBase * 1024, As, Ws, acc);

  const int tid = threadIdx.x;
  const int lane = tid & 63;
  const int wm = (tid >> 6) & 1, wn = tid >> 7;
  const int l15 = lane & 15, quad = lane >> 4;
#pragma unroll
  for (int j = 0; j < 4; ++j) {
    const int gcol = colBase + wn * 64 + j * 16 + l15;
    const float bval = bo[gcol];
#pragma unroll
    for (int i = 0; i < 4; ++i) {
#pragma unroll
      for (int r = 0; r < 4; ++r) {
        int grow = rowBase + wm * 64 + i * 16 + quad * 4 + r;
        out[(size_t)grow * 1024 + gcol] = acc[i][j][r] + bval;
      }
    }
  }
}

extern "C" void kernel_launch(void* const* d_in, const int* in_sizes, int n_in,
                              void* d_out, int out_size, void* d_ws, size_t ws_size,
                              hipStream_t stream) {
  const float* x  = (const float*)d_in[0];
  const float* Wq = (const float*)d_in[1];
  const float* bq = (const float*)d_in[2];
  const float* Wk = (const float*)d_in[3];
  const float* bk = (const float*)d_in[4];
  const float* Wv = (const float*)d_in[5];
  const float* bv = (const float*)d_in[6];
  const float* Wo = (const float*)d_in[7];
  const float* bo = (const float*)d_in[8];
  float* out = (float*)d_out;

  char* ws = (char*)d_ws;
  short* h    = (short*)(ws);                 // 64 MB (reused as att)
  short* Wcat = (short*)(ws + 67108864);      //  8 MB
  short* pq   = (short*)(ws + 75497472);      // 64 MB [B,H,S,dh]
  short* pk   = (short*)(ws + 142606336);     // 64 MB [B,H,S,dh]
  short* v    = (short*)(ws + 209715200);     // 64 MB [B,H,S,dh]
  short* kvW  = (short*)(ws + 276824064);     //  4 MB [bh][e][d]
  float* z    = (float*)(ws + 281018368);     // 64 KB

  prep_h<<<16384, 256, 0, stream>>>(x, h);
  pack_w<<<4096, 256, 0, stream>>>(Wq, Wk, Wv, Wo, Wcat);
  gemm_qkv<<<dim3(24, 256), 256, 0, stream>>>(h, Wcat, bq, bk, bv, pq, pk, v);
  kv_simple<<<256, 256, 0, stream>>>(pk, v, kvW, z);
  attn_kernel<<<dim3(16, 128), 256, 0, stream>>>(pq, kvW, z, h /* att reuses h */);
  gemm_out<<<dim3(8, 256), 256, 0, stream>>>(h, Wcat + 3145728, bo, out);
}